// Round 1
// baseline (404.273 us; speedup 1.0000x reference)
//
#include <hip/hip_runtime.h>

#define B_ 8
#define T_ 256
#define U_ 64
#define U1_ 65
#define V_ 512

// ---------------------------------------------------------------------------
// Kernel 1: per (b,t): for each u, lse over V of (enc[b,t,:] + dec[b,u,:]),
// then blank_lp[b,t,u] = logit(v=0) - lse, emit_lp[b,t,u] = logit(tgt) - lse.
// Block = 256 threads = 4 waves; wave w handles u = w, w+4, ...
// Lane l holds enc v = 4l..4l+3 and v = 256+4l..256+4l+3 (coalesced float4).
// ---------------------------------------------------------------------------
__global__ __launch_bounds__(256) void k_logprobs(
    const float* __restrict__ enc, const float* __restrict__ dec,
    const int* __restrict__ targets,
    float* __restrict__ blank_lp, float* __restrict__ emit_lp)
{
    const int bt   = blockIdx.x;
    const int b    = bt / T_;
    const int t    = bt % T_;
    const int wave = threadIdx.x >> 6;
    const int lane = threadIdx.x & 63;

    const float* erow = enc + (size_t)(b * T_ + t) * V_;
    float4 e0 = *(const float4*)(erow + lane * 4);
    float4 e1 = *(const float4*)(erow + 256 + lane * 4);

    for (int u = wave; u <= U_; u += 4) {
        const float* drow = dec + (size_t)(b * U1_ + u) * V_;
        float4 d0 = *(const float4*)(drow + lane * 4);
        float4 d1 = *(const float4*)(drow + 256 + lane * 4);

        float s = __expf(e0.x + d0.x) + __expf(e0.y + d0.y)
                + __expf(e0.z + d0.z) + __expf(e0.w + d0.w)
                + __expf(e1.x + d1.x) + __expf(e1.y + d1.y)
                + __expf(e1.z + d1.z) + __expf(e1.w + d1.w);

        #pragma unroll
        for (int off = 32; off > 0; off >>= 1)
            s += __shfl_xor(s, off, 64);

        if (lane == 0) {
            float lse = __logf(s);
            // v = 0 lives in lane 0: e0.x (enc), d0.x (dec)
            blank_lp[(b * T_ + t) * U1_ + u] = e0.x + d0.x - lse;
            if (u < U_) {
                int tgt = targets[b * U_ + u];
                float ev = erow[tgt];
                float dv = drow[tgt];
                emit_lp[(b * T_ + t) * U_ + u] = ev + dv - lse;
            }
        }
    }
}

// ---------------------------------------------------------------------------
// Kernel 2: alpha wavefront recursion, one wave per batch.
// Lane u holds alpha[t][u] along anti-diagonal d (t = d - u); lane 63 also
// carries u = 64. alpha[t][u-1] comes from shfl_up(1).
// ---------------------------------------------------------------------------
__device__ __forceinline__ float lae(float x, float y) {
    float m = fmaxf(x, y);
    return m + log1pf(__expf(-fabsf(x - y)));
}

__global__ __launch_bounds__(64) void k_alpha(
    const float* __restrict__ blank_lp, const float* __restrict__ emit_lp,
    const int* __restrict__ il_, const int* __restrict__ tl_,
    float* __restrict__ out)
{
    const int b    = blockIdx.x;
    const int lane = threadIdx.x;
    const int il   = il_[b];
    const int tl   = tl_[b];
    const float* BL = blank_lp + b * T_ * U1_;
    const float* EM = emit_lp  + b * T_ * U_;

    float a  = 0.0f;   // cell value for u = lane
    float a2 = 0.0f;   // lane 63 only: u = 64

    // degenerate case: result sits at (t=0, u=0), diagonal 0
    if (il == 1 && tl == 0 && lane == 0)
        atomicAdd(out, -(a + BL[0]) * (1.0f / B_));

    for (int d = 1; d <= T_ - 1 + U_; ++d) {
        const int u = lane;
        const int t = d - u;
        float aleft = __shfl_up(a, 1, 64);
        float aold  = a;   // lane's value from diagonal d-1 (for lane 63's u=64 cell)

        if (t >= 0 && t < T_) {
            float na;
            if (t == 0) {
                na = aleft + EM[u - 1];                 // t==0 => u=d>=1
            } else if (u == 0) {
                na = a + BL[(t - 1) * U1_];
            } else {
                float x = a     + BL[(t - 1) * U1_ + u];
                float y = aleft + EM[t * U_ + (u - 1)];
                na = lae(x, y);
            }
            a = na;
            if (t == il - 1 && u == tl)
                atomicAdd(out, -(a + BL[(il - 1) * U1_ + tl]) * (1.0f / B_));
        }

        if (lane == 63) {
            const int t2 = d - 64;
            if (t2 >= 0 && t2 < T_) {
                float n2;
                if (t2 == 0) {
                    n2 = aold + EM[63];                 // alpha[0][64]
                } else {
                    float x = a2   + BL[(t2 - 1) * U1_ + 64];
                    float y = aold + EM[t2 * U_ + 63];
                    n2 = lae(x, y);
                }
                a2 = n2;
                if (t2 == il - 1 && 64 == tl)
                    atomicAdd(out, -(a2 + BL[(il - 1) * U1_ + 64]) * (1.0f / B_));
            }
        }
    }
}

extern "C" void kernel_launch(void* const* d_in, const int* in_sizes, int n_in,
                              void* d_out, int out_size, void* d_ws, size_t ws_size,
                              hipStream_t stream)
{
    const float* enc     = (const float*)d_in[0];
    const float* dec     = (const float*)d_in[1];
    const int*   targets = (const int*)d_in[2];
    const int*   il      = (const int*)d_in[3];
    const int*   tl      = (const int*)d_in[4];
    float*       out     = (float*)d_out;

    float* blank_lp = (float*)d_ws;                    // B*T*U1 floats
    float* emit_lp  = blank_lp + B_ * T_ * U1_;        // B*T*U floats

    hipMemsetAsync(d_out, 0, sizeof(float), stream);
    k_logprobs<<<B_ * T_, 256, 0, stream>>>(enc, dec, targets, blank_lp, emit_lp);
    k_alpha<<<B_, 64, 0, stream>>>(blank_lp, emit_lp, il, tl, out);
}

// Round 2
// 127.738 us; speedup vs baseline: 3.1649x; 3.1649x over previous
//
#include <hip/hip_runtime.h>

#define B_ 8
#define T_ 256
#define U_ 64
#define U1_ 65
#define V_ 512
#define NDIAG_ 320   // t+u ranges over [0, T_+U_-1]

// ---------------------------------------------------------------------------
// Kernel 0: edec = exp(dec), elementwise (B*U1*V floats, float4 grid-stride)
// ---------------------------------------------------------------------------
__global__ __launch_bounds__(256) void k_exp(const float* __restrict__ x,
                                             float* __restrict__ y, int n4)
{
    int i = blockIdx.x * blockDim.x + threadIdx.x;
    if (i < n4) {
        float4 v = ((const float4*)x)[i];
        float4 r;
        r.x = __expf(v.x); r.y = __expf(v.y);
        r.z = __expf(v.z); r.w = __expf(v.w);
        ((float4*)y)[i] = r;
    }
}

// ---------------------------------------------------------------------------
// Kernel 1: per (b,t): lse[u] = log( exp(enc_row) . edec_row[u] ), write
//   BLD[b][t+u][u] = enc[0]+dec[u][0]-lse   (diagonal-major, stride 65)
//   EMD[b][t+u][u] = enc[tgt]+dec[u][tgt]-lse (diagonal-major, stride 64)
// Block = 256 threads = 4 waves; wave w handles u = w, w+4, ...
// Lane l holds v = 4l..4l+3 and v = 256+4l..256+4l+3 (coalesced float4).
// ---------------------------------------------------------------------------
__global__ __launch_bounds__(256) void k_logprobs(
    const float* __restrict__ enc, const float* __restrict__ dec,
    const float* __restrict__ edec, const int* __restrict__ targets,
    float* __restrict__ BLD, float* __restrict__ EMD)
{
    const int bt   = blockIdx.x;
    const int b    = bt / T_;
    const int t    = bt % T_;
    const int wave = threadIdx.x >> 6;
    const int lane = threadIdx.x & 63;

    const float* erow = enc + (size_t)(b * T_ + t) * V_;
    float4 e0 = *(const float4*)(erow + lane * 4);
    float4 e1 = *(const float4*)(erow + 256 + lane * 4);
    float4 x0, x1;
    x0.x = __expf(e0.x); x0.y = __expf(e0.y); x0.z = __expf(e0.z); x0.w = __expf(e0.w);
    x1.x = __expf(e1.x); x1.y = __expf(e1.y); x1.z = __expf(e1.z); x1.w = __expf(e1.w);

    for (int u = wave; u <= U_; u += 4) {
        const float* xdrow = edec + (size_t)(b * U1_ + u) * V_;
        float4 d0 = *(const float4*)(xdrow + lane * 4);
        float4 d1 = *(const float4*)(xdrow + 256 + lane * 4);

        // two parallel FMA chains for ILP, then combine
        float sA = x0.x * d0.x;
        float sB = x1.x * d1.x;
        sA = fmaf(x0.y, d0.y, sA);  sB = fmaf(x1.y, d1.y, sB);
        sA = fmaf(x0.z, d0.z, sA);  sB = fmaf(x1.z, d1.z, sB);
        sA = fmaf(x0.w, d0.w, sA);  sB = fmaf(x1.w, d1.w, sB);
        float s = sA + sB;

        #pragma unroll
        for (int off = 32; off > 0; off >>= 1)
            s += __shfl_xor(s, off, 64);

        if (lane == 0) {
            float lse = __logf(s);
            const float* drow = dec + (size_t)(b * U1_ + u) * V_;
            const int dg = t + u;
            BLD[((size_t)b * NDIAG_ + dg) * U1_ + u] = e0.x + drow[0] - lse;
            if (u < U_) {
                int tgt = targets[b * U_ + u];
                EMD[((size_t)b * NDIAG_ + dg) * U_ + u] = erow[tgt] + drow[tgt] - lse;
            }
        }
    }
}

// ---------------------------------------------------------------------------
// Kernel 2: alpha wavefront recursion, one wave per batch, diagonal-major
// inputs so each diagonal's operands are two coalesced loads. Prefetched in
// groups of 4 diagonals, double-buffered in named register sets.
// ---------------------------------------------------------------------------
__device__ __forceinline__ float lae(float x, float y) {
    float m = fmaxf(x, y);
    return m + __logf(1.0f + __expf(-fabsf(x - y)));
}

#define LOADG(PB, PE, PX, g_) do {                                   \
    const float* blr = BLb + (size_t)((g_) * 4) * U1_;               \
    const float* emr = EMb + (size_t)((g_) * 4) * U_;                \
    _Pragma("unroll")                                                \
    for (int j = 0; j < 4; ++j) {                                    \
        PB[j] = blr[j * U1_ + lane];                                 \
        PE[j] = emr[j * U_ + lane];                                  \
        PX[j] = blr[j * U1_ + 64];                                   \
    }                                                                \
} while (0)

#define COMPG(PB, PE, PX, g_) do {                                   \
    _Pragma("unroll")                                                \
    for (int j = 0; j < 4; ++j) {                                    \
        const int d = 4 * (g_) + 1 + j;                              \
        float em    = __shfl_up(PE[j], 1, 64);                       \
        float aleft = __shfl_up(a, 1, 64);                           \
        float aold  = a;                                             \
        const int t = d - lane;                                      \
        if (t >= 0 && t < T_) {                                      \
            float na;                                                \
            if (t == 0)          na = aleft + em;                    \
            else if (lane == 0)  na = a + PB[j];                     \
            else                 na = lae(a + PB[j], aleft + em);    \
            a = na;                                                  \
            if (t == il - 1 && lane == tl)                           \
                atomicAdd(out, -(a + BLb[(size_t)(il-1+tl)*U1_ + tl]) * (1.0f/B_)); \
        }                                                            \
        if (lane == 63) {                                            \
            const int t2 = d - 64;                                   \
            if (t2 >= 0 && t2 < T_) {                                \
                float y2 = aold + PE[j];                             \
                a2 = (t2 == 0) ? y2 : lae(a2 + PX[j], y2);           \
                if (t2 == il - 1 && 64 == tl)                        \
                    atomicAdd(out, -(a2 + BLb[(size_t)(il-1+tl)*U1_ + tl]) * (1.0f/B_)); \
            }                                                        \
        }                                                            \
    }                                                                \
} while (0)

__global__ __launch_bounds__(64) void k_alpha(
    const float* __restrict__ BLD, const float* __restrict__ EMD,
    const int* __restrict__ il_, const int* __restrict__ tl_,
    float* __restrict__ out)
{
    const int b    = blockIdx.x;
    const int lane = threadIdx.x;
    const int il   = il_[b];
    const int tl   = tl_[b];
    const float* BLb = BLD + (size_t)b * NDIAG_ * U1_;
    const float* EMb = EMD + (size_t)b * NDIAG_ * U_;

    float a  = 0.0f;   // alpha for u = lane (latest diagonal)
    float a2 = 0.0f;   // lane 63 only: u = 64

    if (il == 1 && tl == 0 && lane == 0)
        atomicAdd(out, -(a + BLb[0]) * (1.0f / B_));

    float pbA[4], peA[4], pxA[4];
    float pbB[4], peB[4], pxB[4];

    // 80 groups of 4 diagonals cover d = 1..320 (d=320 self-gates: t >= T_)
    LOADG(pbA, peA, pxA, 0);
    for (int g = 0; g < 80; g += 2) {
        LOADG(pbB, peB, pxB, g + 1);
        COMPG(pbA, peA, pxA, g);
        if (g + 2 < 80) LOADG(pbA, peA, pxA, g + 2);
        COMPG(pbB, peB, pxB, g + 1);
    }
}

extern "C" void kernel_launch(void* const* d_in, const int* in_sizes, int n_in,
                              void* d_out, int out_size, void* d_ws, size_t ws_size,
                              hipStream_t stream)
{
    const float* enc     = (const float*)d_in[0];
    const float* dec     = (const float*)d_in[1];
    const int*   targets = (const int*)d_in[2];
    const int*   il      = (const int*)d_in[3];
    const int*   tl      = (const int*)d_in[4];
    float*       out     = (float*)d_out;

    float* edec = (float*)d_ws;                          // B*U1*V
    float* BLD  = edec + (size_t)B_ * U1_ * V_;          // B*NDIAG*U1
    float* EMD  = BLD  + (size_t)B_ * NDIAG_ * U1_;      // B*NDIAG*U

    hipMemsetAsync(d_out, 0, sizeof(float), stream);

    const int n4 = B_ * U1_ * V_ / 4;
    k_exp<<<(n4 + 255) / 256, 256, 0, stream>>>(dec, edec, n4);
    k_logprobs<<<B_ * T_, 256, 0, stream>>>(enc, dec, edec, targets, BLD, EMD);
    k_alpha<<<B_, 64, 0, stream>>>(BLD, EMD, il, tl, out);
}

// Round 4
// 111.930 us; speedup vs baseline: 3.6118x; 1.1412x over previous
//
#include <hip/hip_runtime.h>

#define B_ 8
#define T_ 256
#define U_ 64
#define U1_ 65
#define V_ 512
#define NDIAG_ 320    // valid diagonals: t+u in [0, 319]
#define NDIAGP_ 336   // padded so prefetch over-issue stays in-bounds
#define NT_ 4         // t-rows per k_logprobs block

#define LOG2E_ 1.4426950408889634f
#define LN2_   0.6931471805599453f

// ---------------------------------------------------------------------------
// Kernel 0: edec = exp(dec), elementwise (B*U1*V floats, float4)
// ---------------------------------------------------------------------------
__global__ __launch_bounds__(256) void k_exp(const float* __restrict__ x,
                                             float* __restrict__ y, int n4)
{
    int i = blockIdx.x * blockDim.x + threadIdx.x;
    if (i < n4) {
        float4 v = ((const float4*)x)[i];
        float4 r;
        r.x = __expf(v.x); r.y = __expf(v.y);
        r.z = __expf(v.z); r.w = __expf(v.w);
        ((float4*)y)[i] = r;
    }
}

// ---------------------------------------------------------------------------
// Kernel 1: block = (b, group of 4 t's). lse[u] = log2( exp(enc_row) . edec_row[u] ).
// Writes diagonal-major log2-domain:
//   BLD[b][t+u][u] = (enc[0]+dec[u][0])*log2e   - lse2
//   EMD[b][t+u][u] = (enc[tgt]+dec[u][tgt])*log2e - lse2
// b = blockIdx.x % 8 so batch b's blocks land on XCD b (round-robin dispatch),
// matching k_alpha's block b -> XCD b for L2 locality.
// ---------------------------------------------------------------------------
__global__ __launch_bounds__(256) void k_logprobs(
    const float* __restrict__ enc, const float* __restrict__ dec,
    const float* __restrict__ edec, const int* __restrict__ targets,
    float* __restrict__ BLD, float* __restrict__ EMD)
{
    const int blk  = blockIdx.x;           // 0 .. B_*T_/NT_ - 1 (512)
    const int b    = blk % B_;
    const int tg   = blk / B_;
    const int t0   = tg * NT_;
    const int wave = threadIdx.x >> 6;
    const int lane = threadIdx.x & 63;

    // exp(enc) rows for NT_ t's, in registers (static indexing via unroll)
    float4 xe0[NT_], xe1[NT_];
    #pragma unroll
    for (int j = 0; j < NT_; ++j) {
        const float* erow = enc + (size_t)(b * T_ + t0 + j) * V_;
        float4 e0 = *(const float4*)(erow + lane * 4);
        float4 e1 = *(const float4*)(erow + 256 + lane * 4);
        xe0[j].x = __expf(e0.x); xe0[j].y = __expf(e0.y);
        xe0[j].z = __expf(e0.z); xe0[j].w = __expf(e0.w);
        xe1[j].x = __expf(e1.x); xe1[j].y = __expf(e1.y);
        xe1[j].z = __expf(e1.z); xe1[j].w = __expf(e1.w);
    }

    for (int u = wave; u <= U_; u += 4) {
        const float* xdrow = edec + (size_t)(b * U1_ + u) * V_;
        float4 d0 = *(const float4*)(xdrow + lane * 4);
        float4 d1 = *(const float4*)(xdrow + 256 + lane * 4);

        float s[NT_];
        #pragma unroll
        for (int j = 0; j < NT_; ++j) {
            float sA = xe0[j].x * d0.x;
            float sB = xe1[j].x * d1.x;
            sA = fmaf(xe0[j].y, d0.y, sA);  sB = fmaf(xe1[j].y, d1.y, sB);
            sA = fmaf(xe0[j].z, d0.z, sA);  sB = fmaf(xe1[j].z, d1.z, sB);
            sA = fmaf(xe0[j].w, d0.w, sA);  sB = fmaf(xe1[j].w, d1.w, sB);
            s[j] = sA + sB;
        }

        #pragma unroll
        for (int off = 32; off > 0; off >>= 1) {
            #pragma unroll
            for (int j = 0; j < NT_; ++j)
                s[j] += __shfl_xor(s[j], off, 64);
        }

        if (lane == 0) {
            const float* dr = dec + (size_t)(b * U1_ + u) * V_;
            const float d_blank = dr[0];
            int   tgt = 0;
            float d_tgt = 0.0f;
            if (u < U_) { tgt = targets[b * U_ + u]; d_tgt = dr[tgt]; }
            #pragma unroll
            for (int j = 0; j < NT_; ++j) {
                const int t  = t0 + j;
                const int dg = t + u;
                const float lse2 = log2f(s[j]);
                const float* er = enc + (size_t)(b * T_ + t) * V_;
                BLD[((size_t)b * NDIAGP_ + dg) * U1_ + u] =
                    (er[0] + d_blank) * LOG2E_ - lse2;
                if (u < U_)
                    EMD[((size_t)b * NDIAGP_ + dg) * U_ + u] =
                        (er[tgt] + d_tgt) * LOG2E_ - lse2;
            }
        }
    }
}

// ---------------------------------------------------------------------------
// Kernel 2: alpha wavefront recursion (log2 domain), one wave per batch.
// Depth-4 register prefetch pipeline: compute group g while g+1..g+3 in flight.
// ---------------------------------------------------------------------------
__device__ __forceinline__ float lae2(float x, float y) {
    float m = fmaxf(x, y);
    return m + log2f(1.0f + exp2f(-fabsf(x - y)));
}

#define LOADG(PB, PE, PX, g_) do {                                   \
    const float* blr = BLb + (size_t)((g_) * 4) * U1_;               \
    const float* emr = EMb + (size_t)((g_) * 4) * U_;                \
    _Pragma("unroll")                                                \
    for (int j = 0; j < 4; ++j) {                                    \
        PB[j] = blr[j * U1_ + lane];                                 \
        PE[j] = emr[j * U_ + lane];                                  \
        PX[j] = blr[j * U1_ + 64];                                   \
    }                                                                \
} while (0)

#define COMPG(PB, PE, PX, g_) do {                                   \
    _Pragma("unroll")                                                \
    for (int j = 0; j < 4; ++j) {                                    \
        const int d = 4 * (g_) + 1 + j;                              \
        float em    = __shfl_up(PE[j], 1, 64);                       \
        float aleft = __shfl_up(a, 1, 64);                           \
        float aold  = a;                                             \
        const int t = d - lane;                                      \
        if (t >= 0 && t < T_) {                                      \
            float na;                                                \
            if (t == 0)          na = aleft + em;                    \
            else if (lane == 0)  na = a + PB[j];                     \
            else                 na = lae2(a + PB[j], aleft + em);   \
            a = na;                                                  \
            if (t == il - 1 && lane == tl)                           \
                atomicAdd(out, -(a + BLb[(size_t)(il-1+tl)*U1_ + tl]) * (LN2_/B_)); \
        }                                                            \
        if (lane == 63) {                                            \
            const int t2 = d - 64;                                   \
            if (t2 >= 0 && t2 < T_) {                                \
                float y2 = aold + PE[j];                             \
                a2 = (t2 == 0) ? y2 : lae2(a2 + PX[j], y2);          \
                if (t2 == il - 1 && 64 == tl)                        \
                    atomicAdd(out, -(a2 + BLb[(size_t)(il-1+tl)*U1_ + tl]) * (LN2_/B_)); \
            }                                                        \
        }                                                            \
    }                                                                \
} while (0)

__global__ __launch_bounds__(64) void k_alpha(
    const float* __restrict__ BLD, const float* __restrict__ EMD,
    const int* __restrict__ il_, const int* __restrict__ tl_,
    float* __restrict__ out)
{
    const int b    = blockIdx.x;
    const int lane = threadIdx.x;
    const int il   = il_[b];
    const int tl   = tl_[b];
    const float* BLb = BLD + (size_t)b * NDIAGP_ * U1_;
    const float* EMb = EMD + (size_t)b * NDIAGP_ * U_;

    float a  = 0.0f;   // alpha (log2) for u = lane
    float a2 = 0.0f;   // lane 63 only: u = 64

    if (il == 1 && tl == 0 && lane == 0)
        atomicAdd(out, -(a + BLb[0]) * (LN2_ / B_));

    float pbA[4], peA[4], pxA[4];
    float pbB[4], peB[4], pxB[4];
    float pbC[4], peC[4], pxC[4];
    float pbD[4], peD[4], pxD[4];

    // 80 groups of 4 diagonals cover d = 1..320 (d=320 self-gates: t >= T_).
    // Prefetch over-issues up to group 82 -> reads padded region, never used.
    LOADG(pbA, peA, pxA, 0);
    LOADG(pbB, peB, pxB, 1);
    LOADG(pbC, peC, pxC, 2);
    for (int g = 0; g < 80; g += 4) {
        LOADG(pbD, peD, pxD, g + 3);  COMPG(pbA, peA, pxA, g);
        LOADG(pbA, peA, pxA, g + 4);  COMPG(pbB, peB, pxB, g + 1);
        LOADG(pbB, peB, pxB, g + 5);  COMPG(pbC, peC, pxC, g + 2);
        LOADG(pbC, peC, pxC, g + 6);  COMPG(pbD, peD, pxD, g + 3);
    }
}

extern "C" void kernel_launch(void* const* d_in, const int* in_sizes, int n_in,
                              void* d_out, int out_size, void* d_ws, size_t ws_size,
                              hipStream_t stream)
{
    const float* enc     = (const float*)d_in[0];
    const float* dec     = (const float*)d_in[1];
    const int*   targets = (const int*)d_in[2];
    const int*   il      = (const int*)d_in[3];
    const int*   tl      = (const int*)d_in[4];
    float*       out     = (float*)d_out;

    float* edec = (float*)d_ws;                           // B*U1*V
    float* BLD  = edec + (size_t)B_ * U1_ * V_;           // B*NDIAGP*U1
    float* EMD  = BLD  + (size_t)B_ * NDIAGP_ * U1_;      // B*NDIAGP*U

    (void)hipMemsetAsync(d_out, 0, sizeof(float), stream);

    const int n4 = B_ * U1_ * V_ / 4;
    k_exp<<<(n4 + 255) / 256, 256, 0, stream>>>(dec, edec, n4);
    k_logprobs<<<B_ * T_ / NT_, 256, 0, stream>>>(enc, dec, edec, targets, BLD, EMD);
    k_alpha<<<B_, 64, 0, stream>>>(BLD, EMD, il, tl, out);
}